// Round 29
// baseline (956.563 us; speedup 1.0000x reference)
//
#include <hip/hip_runtime.h>
#include <hip/hip_fp16.h>
#include <cstdio>

typedef _Float16 f16;
typedef _Float16 f16x8 __attribute__((ext_vector_type(8)));
typedef _Float16 f16x4 __attribute__((ext_vector_type(4)));
typedef float f32x4 __attribute__((ext_vector_type(4)));

#define DI __device__ __forceinline__

DI void gload_lds16(const void* g, void* l) {
  __builtin_amdgcn_global_load_lds(
      (const __attribute__((address_space(1))) void*)g,
      (__attribute__((address_space(3))) void*)l, 16, 0, 0);
}

// XCD-aware block swizzle (bijective when gridDim.x % 8 == 0) [T1]
DI int xcd_swz() {
  int nwg = gridDim.x, bid = blockIdx.x;
  if ((nwg & 7) == 0) bid = (bid & 7) * (nwg >> 3) + (bid >> 3);
  return bid;
}

// q/k/v plane offsets within the packed qkv region (f16 elements)
#define QK_PLANE 16777216   // 16384*1024

// ---------------- cast f32 -> f16, 4 elems/thread ----------------
__global__ void k_cast(const float* __restrict__ in, f16* __restrict__ out, int n4) {
  int i = blockIdx.x * blockDim.x + threadIdx.x;
  if (i >= n4) return;
  float4 v = ((const float4*)in)[i];
  f16x4 o;
  o[0] = (f16)v.x; o[1] = (f16)v.y; o[2] = (f16)v.z; o[3] = (f16)v.w;
  ((f16x4*)out)[i] = o;
}

// ---- O32 strips (in S upper halves) summed in FIXED order -> xo f16 rows --------
__global__ void k_o_cast(const float* __restrict__ S, f16* __restrict__ xo,
                         int q0, int q1, int SPLIT) {
  int R = q1 - q0;
  int i = blockIdx.x * blockDim.x + threadIdx.x;   // 2R * 256 threads
  int grow = i >> 8;
  int c4 = (i & 255) * 4;
  const float* strip = S + (size_t)grow * q1 + (q1 >> 1);
  float4 v = *(const float4*)(strip + c4);
  if (SPLIT > 1) {
    float4 v1 = *(const float4*)(strip + 1024 + c4);
    v.x += v1.x; v.y += v1.y; v.z += v1.z; v.w += v1.w;
  }
  if (SPLIT > 2) {
    float4 v2 = *(const float4*)(strip + 2048 + c4);
    v.x += v2.x; v.y += v2.y; v.z += v2.z; v.w += v2.w;
  }
  int b = (grow >= R) ? 1 : 0;
  int qloc = grow - b * R;
  f16x4 o;
  o[0] = (f16)v.x; o[1] = (f16)v.y; o[2] = (f16)v.z; o[3] = (f16)v.w;
  *(f16x4*)(xo + (size_t)(b * 8192 + q0 + qloc) * 1024 + c4) = o;
}

// ---------------- RoPE in-place on separate q/k planes (stride 1024) -------------
__global__ void k_rope(f16* __restrict__ qkv) {
  int gid = blockIdx.x * blockDim.x + threadIdx.x;  // 16384 * 64
  int tt = gid >> 6, j0 = (gid & 63) * 8;
  int t = tt & 8191;
  f16* rowq = qkv + (size_t)tt * 1024;
  f16* rowk = qkv + QK_PLANE + (size_t)tt * 1024;
  f16x8 qa = *(f16x8*)(rowq + j0), qb = *(f16x8*)(rowq + 512 + j0);
  f16x8 ka = *(f16x8*)(rowk + j0), kb = *(f16x8*)(rowk + 512 + j0);
  #pragma unroll
  for (int u = 0; u < 8; ++u) {
    int j = j0 + u;
    float invf = powf(10000.0f, -(float)j * (1.0f / 512.0f));
    float s, c;
    sincosf((float)t * invf, &s, &c);
    float q0v = (float)qa[u], q1v = (float)qb[u];
    qa[u] = (f16)(q0v * c - q1v * s); qb[u] = (f16)(q1v * c + q0v * s);
    float k0v = (float)ka[u], k1v = (float)kb[u];
    ka[u] = (f16)(k0v * c - k1v * s); kb[u] = (f16)(k1v * c + k0v * s);
  }
  *(f16x8*)(rowq + j0) = qa; *(f16x8*)(rowq + 512 + j0) = qb;
  *(f16x8*)(rowk + j0) = ka; *(f16x8*)(rowk + 512 + j0) = kb;
}

// ---------------- V transpose: v plane -> vt PANEL-MAJOR [t/32][d][32] ----------
__global__ __launch_bounds__(256) void k_transpose(const f16* __restrict__ qkv, f16* __restrict__ vt) {
  __shared__ f16 tile[64][72];
  int bid = blockIdx.x;            // 2 * 128 * 16
  int b = bid >> 11;
  int rem = bid & 2047;
  int tb = (rem >> 4) * 64;        // token base
  int db = (rem & 15) * 64;        // d base
  int tid = threadIdx.x;
  int r = tid >> 2, c0 = (tid & 3) * 16;
  const f16* src = qkv + (size_t)2 * QK_PLANE + (size_t)(b * 8192 + tb + r) * 1024 + db + c0;
  #pragma unroll
  for (int ii = 0; ii < 16; ++ii) tile[r][c0 + ii] = src[ii];
  __syncthreads();
  int p = (tb + c0) >> 5;
  int t5 = (tb + c0) & 31;
  f16* dst = vt + (size_t)b * 8388608 + (size_t)p * 32768 + (size_t)(db + r) * 32 + t5;
  #pragma unroll
  for (int ii = 0; ii < 16; ++ii) dst[ii] = tile[c0 + ii][r];
}

// -------- chunk softmax: pass1 from Pstat partials; pass2 in-place S->P ----------
__global__ __launch_bounds__(256)
void k_softmax_c(float* __restrict__ S, const float2* __restrict__ Pstat, int q0, int q1) {
  int R = q1 - q0;
  int row = blockIdx.x * 4 + (threadIdx.x >> 6);  // 0..2R-1
  int lane = threadIdx.x & 63;
  int b = (row >= R) ? 1 : 0;
  int qloc = row - b * R;
  int qg = q0 + qloc;
  float* Srow = S + (size_t)row * q1;
  int nvalid = qg + 1;
  int djb = qg >> 7;                // last valid 128-col block for this row

  float2 st = make_float2(-INFINITY, 0.f);
  if (lane <= djb) st = Pstat[(size_t)row * 64 + lane];
  float m = st.x;
  #pragma unroll
  for (int msk = 32; msk >= 1; msk >>= 1) m = fmaxf(m, __shfl_xor(m, msk));
  float contrib = (lane <= djb) ? st.y * __expf(st.x - m) : 0.f;
  #pragma unroll
  for (int msk = 32; msk >= 1; msk >>= 1) contrib += __shfl_xor(contrib, msk);
  float ssum = contrib;

  float rinv = 0.03125f / ssum;  // 1024^-0.5 applied post-softmax (reference quirk)
  int klim = (qg | 127) + 1;     // zero-fill to PV's k-tile boundary
  f16* Prow = (f16*)Srow;
  for (int kk = lane * 4; kk < klim; kk += 256) {
    float4 v = *(const float4*)(Srow + kk);
    asm volatile("" ::: "memory");  // keep f32 load before aliasing f16 store
    f16x4 o;
    o[0] = (f16)((kk     < nvalid) ? __expf(v.x - m) * rinv : 0.f);
    o[1] = (f16)((kk + 1 < nvalid) ? __expf(v.y - m) * rinv : 0.f);
    o[2] = (f16)((kk + 2 < nvalid) ? __expf(v.z - m) * rinv : 0.f);
    o[3] = (f16)((kk + 3 < nvalid) ? __expf(v.w - m) * rinv : 0.f);
    *(f16x4*)(Prow + kk) = o;
  }
}

// ==== gemm_256: 256x256 tile, 8 waves, BK=32, ring-4, counted vmcnt [T3/T4] + T2 ====
// MODE 1: qkv proj -> separate q/k/v planes (bn>>2 selects plane), fp16
// MODE 4: out = o @ w_proj^T + b -> fp32
template <int MODE>
__global__ __launch_bounds__(512)
void gemm_256(const f16* __restrict__ A, const f16* __restrict__ B,
              void* __restrict__ C, const float* __restrict__ bias)
{
  __shared__ __align__(16) f16 As[4][8192];
  __shared__ __align__(16) f16 Bs[4][8192];

  const int tid = threadIdx.x;
  const int w = tid >> 6;
  const int l = tid & 63;
  const int wm = w >> 2;
  const int wn = w & 3;
  const int bid = xcd_swz();

  int bm, bn;
  if constexpr (MODE == 1) {
    int grp = bid >> 3, off = bid & 7;
    bm = (grp / 6) * 4 + (off >> 1);
    bn = (grp % 6) * 2 + (off & 1);
  } else {
    bm = bid >> 2; bn = bid & 3;
  }
  const int nk = 32;
  const f16* Abase = A + (size_t)bm * 256 * 1024;
  const f16* Bbase = B + (size_t)bn * 256 * 1024;

  f32x4 acc[8][4];
  #pragma unroll
  for (int m = 0; m < 8; ++m)
    #pragma unroll
    for (int n = 0; n < 4; ++n) { acc[m][n][0]=0.f; acc[m][n][1]=0.f; acc[m][n][2]=0.f; acc[m][n][3]=0.f; }

  const int srow = tid >> 2;
  const int swz = ((tid & 3) ^ ((tid >> 3) & 3)) * 8;   // T2 writer-side
  const f16* gA0 = Abase + (size_t)srow * 1024 + swz;
  const f16* gA1 = gA0 + (size_t)128 * 1024;
  const f16* gB0 = Bbase + (size_t)srow * 1024 + swz;
  const f16* gB1 = gB0 + (size_t)128 * 1024;
  const int ldst = tid * 8;

  const int pch = (l >> 4) ^ (((l & 15) >> 1) & 3);     // T2 reader-side
  const int aoffb = (wm * 128 + (l & 15)) * 32 + pch * 8;
  const int boffb = (wn * 64 + (l & 15)) * 32 + pch * 8;

#define STAGE(slot, t) do { \
    const size_t _o = (size_t)(t) * 32; \
    f16* _as = As[slot]; f16* _bs = Bs[slot]; \
    gload_lds16(gA0 + _o, _as + ldst); \
    gload_lds16(gA1 + _o, _as + 4096 + ldst); \
    gload_lds16(gB0 + _o, _bs + ldst); \
    gload_lds16(gB1 + _o, _bs + 4096 + ldst); } while (0)
#define COMPUTE(slot) do { \
    const f16* pa = As[slot] + aoffb; \
    const f16* pb = Bs[slot] + boffb; \
    f16x8 av[8], bv[4]; \
    _Pragma("unroll") for (int m = 0; m < 8; ++m) av[m] = *(const f16x8*)(pa + m * 512); \
    _Pragma("unroll") for (int n = 0; n < 4; ++n) bv[n] = *(const f16x8*)(pb + n * 512); \
    _Pragma("unroll") for (int m = 0; m < 8; ++m) \
      _Pragma("unroll") for (int n = 0; n < 4; ++n) \
        acc[m][n] = __builtin_amdgcn_mfma_f32_16x16x32_f16(av[m], bv[n], acc[m][n], 0, 0, 0); \
  } while (0)

  STAGE(0, 0); STAGE(1, 1);
  for (int i = 0; i < nk; ++i) {
    int ts = (i + 2 < nk) ? i + 2 : nk - 1;
    STAGE((i + 2) & 3, ts);
    asm volatile("s_waitcnt vmcnt(8)" ::: "memory");
    __builtin_amdgcn_s_barrier();
    COMPUTE(i & 3);
  }
#undef STAGE
#undef COMPUTE

  const int rg = (l >> 4) * 4;
  #pragma unroll
  for (int m = 0; m < 8; ++m) {
    #pragma unroll
    for (int n = 0; n < 4; ++n) {
      f32x4 v = acc[m][n];
      size_t colg = (size_t)bn * 256 + wn * 64 + n * 16 + (l & 15);
      #pragma unroll
      for (int r = 0; r < 4; ++r) {
        size_t roww = (size_t)bm * 256 + wm * 128 + m * 16 + rg + r;
        if constexpr (MODE == 1) {
          // route to q/k/v plane: bn in [0,12), each 256-col tile within one plane
          f16* dst = (f16*)C + (size_t)(bn >> 2) * QK_PLANE;
          size_t col = colg & 1023;
          dst[roww * 1024 + col] = (f16)(v[r] + bias[colg]);
        } else {
          ((float*)C)[roww * 1024 + colg] = v[r] + bias[colg];
        }
      }
    }
  }
}

// ==== gemm_s256: S-GEMM, 256x256 tile, 8 waves, 2-PHASE syncthreads ping-pong ====
// A = q plane, B = k plane (stride 1024). S written with NON-TEMPORAL stores so the
// 78 MB/dispatch S stream does not evict the L3-resident q/k panels (the measured
// 2-3x input over-fetch mechanism). Same values/addresses/order -> bitwise output.
__global__ __launch_bounds__(512)
void gemm_s256(const f16* __restrict__ A, float* __restrict__ S,
               float2* __restrict__ Pstat, int q0, int q1)
{
  __shared__ __align__(16) f16 As0[8192];   // 256x32 f16 = 16 KB
  __shared__ __align__(16) f16 As1[8192];
  __shared__ __align__(16) f16 Bs0[8192];
  __shared__ __align__(16) f16 Bs1[8192];   // total 64 KB -> 2 blocks/CU

  const int tid = threadIdx.x;
  const int w = tid >> 6;
  const int l = tid & 63;
  const int wm = w >> 2;
  const int wn = w & 3;
  const int bid = xcd_swz();
  const int R = q1 - q0;
  const int nqt = R >> 8, ncb = q1 >> 8;

  int b = bid / (nqt * ncb);
  int rem = bid % (nqt * ncb);
  int qb = rem / ncb, jb = rem % ncb;
  const int jdiag = (q0 >> 8) + qb;
  if (jb > jdiag) return;             // fully-masked (block-uniform, pre-barrier)

  const f16* Abase = A + (size_t)(b * 8192 + q0 + qb * 256) * 1024;              // q rows
  const f16* Bbase = A + QK_PLANE + (size_t)(b * 8192 + jb * 256) * 1024;        // k rows
  const size_t crow0 = (size_t)(b * R + qb * 256);
  const int nk = 32;

  f32x4 acc[8][4];
  #pragma unroll
  for (int m = 0; m < 8; ++m)
    #pragma unroll
    for (int n = 0; n < 4; ++n) { acc[m][n][0]=0.f; acc[m][n][1]=0.f; acc[m][n][2]=0.f; acc[m][n][3]=0.f; }

  const int srow = tid >> 2;
  const int swz = ((tid & 3) ^ ((tid >> 3) & 3)) * 8;   // T2 writer-side
  const f16* gA0 = Abase + (size_t)srow * 1024 + swz;
  const f16* gA1 = gA0 + (size_t)128 * 1024;
  const f16* gB0 = Bbase + (size_t)srow * 1024 + swz;
  const f16* gB1 = gB0 + (size_t)128 * 1024;
  const int ldst = tid * 8;

  const int pch = (l >> 4) ^ (((l & 15) >> 1) & 3);     // T2 reader-side
  const int aoffb = (wm * 128 + (l & 15)) * 32 + pch * 8;
  const int boffb = (wn * 64 + (l & 15)) * 32 + pch * 8;

#define STAGE0() do { \
    gload_lds16(gA0, As0 + ldst); gload_lds16(gA1, As0 + 4096 + ldst); \
    gload_lds16(gB0, Bs0 + ldst); gload_lds16(gB1, Bs0 + 4096 + ldst); } while (0)
#define STAGE1() do { \
    gload_lds16(gA0, As1 + ldst); gload_lds16(gA1, As1 + 4096 + ldst); \
    gload_lds16(gB0, Bs1 + ldst); gload_lds16(gB1, Bs1 + 4096 + ldst); } while (0)
#define ADV() do { gA0 += 32; gA1 += 32; gB0 += 32; gB1 += 32; } while (0)
#define COMPUTE(as_, bs_) do { \
    const f16* pa = (as_) + aoffb; \
    const f16* pb = (bs_) + boffb; \
    f16x8 av[8], bv[4]; \
    _Pragma("unroll") for (int m = 0; m < 8; ++m) av[m] = *(const f16x8*)(pa + m * 512); \
    _Pragma("unroll") for (int n = 0; n < 4; ++n) bv[n] = *(const f16x8*)(pb + n * 512); \
    _Pragma("unroll") for (int m = 0; m < 8; ++m) \
      _Pragma("unroll") for (int n = 0; n < 4; ++n) \
        acc[m][n] = __builtin_amdgcn_mfma_f32_16x16x32_f16(av[m], bv[n], acc[m][n], 0, 0, 0); \
  } while (0)

  STAGE0(); ADV();
  __syncthreads();
  for (int it = 0; it + 2 <= nk; it += 2) {
    STAGE1(); ADV();
    COMPUTE(As0, Bs0);
    __syncthreads();
    if (it + 2 < nk) { STAGE0(); }
    ADV();
    COMPUTE(As1, Bs1);
    __syncthreads();
  }
#undef STAGE0
#undef STAGE1
#undef ADV
#undef COMPUTE

  const int rg = (l >> 4) * 4;  // C/D: col = lane&15, row = (lane>>4)*4 + reg
  // ---- S write: n-innermost, NON-TEMPORAL (stream past L2/L3, no allocation) ----
  #pragma unroll
  for (int m = 0; m < 8; ++m) {
    #pragma unroll
    for (int r = 0; r < 4; ++r) {
      size_t roww = crow0 + wm * 128 + m * 16 + rg + r;
      float* sp = S + roww * q1 + (size_t)jb * 256 + wn * 64 + (l & 15);
      #pragma unroll
      for (int n = 0; n < 4; ++n)
        __builtin_nontemporal_store(acc[m][n][r], sp + n * 16);
    }
  }

  // ---- Pstat partials: reuse dead LDS (As0 = max, Bs0 = sums), fixed order ----
  __syncthreads();                       // all waves past last LDS tile reads
  float* redmax = (float*)As0;           // [4][256] f32 (wn-indexed)
  float* redsum = (float*)Bs0;           // [4][256] f32
  const bool diag = (jb == jdiag);
  const int cbase = jb * 256 + wn * 64 + (l & 15);
  const int rbase = q0 + qb * 256 + wm * 128;

  // pass 1: per-row masked max over this lane's 4 cols, shfl over 16-lane col group
  #pragma unroll
  for (int m = 0; m < 8; ++m) {
    float vm[4];
    #pragma unroll
    for (int r = 0; r < 4; ++r) {
      int row_g = rbase + m * 16 + rg + r;
      float best = -INFINITY;
      #pragma unroll
      for (int n = 0; n < 4; ++n) {
        bool valid = !diag || (cbase + n * 16 <= row_g);
        if (valid) best = fmaxf(best, acc[m][n][r]);
      }
      vm[r] = best;
    }
    #pragma unroll
    for (int r = 0; r < 4; ++r)
      #pragma unroll
      for (int msk = 1; msk <= 8; msk <<= 1)
        vm[r] = fmaxf(vm[r], __shfl_xor(vm[r], msk));
    if ((l & 15) == 0) {
      #pragma unroll
      for (int r = 0; r < 4; ++r)
        redmax[wn * 256 + wm * 128 + m * 16 + rg + r] = vm[r];
    }
  }
  __syncthreads();

  // pass 2: sumexp with the 128-block max (pair of wn quarters), shfl, store
  #pragma unroll
  for (int m = 0; m < 8; ++m) {
    float vs[4];
    #pragma unroll
    for (int r = 0; r < 4; ++r) {
      int rr = wm * 128 + m * 16 + rg + r;
      float Mv = fmaxf(redmax[(wn & ~1) * 256 + rr], redmax[(wn | 1) * 256 + rr]);
      int row_g = rbase + m * 16 + rg + r;
      float s = 0.f;
      #pragma unroll
      for (int n = 0; n < 4; ++n) {
        bool valid = !diag || (cbase + n * 16 <= row_g);
        if (valid) s += __expf(acc[m][n][r] - Mv);
      }
      vs[r] = s;
    }
    #pragma unroll
    for (int r = 0; r < 4; ++r)
      #pragma unroll
      for (int msk = 1; msk <= 8; msk <<= 1)
        vs[r] += __shfl_xor(vs[r], msk);
    if ((l & 15) == 0) {
      #pragma unroll
      for (int r = 0; r < 4; ++r)
        redsum[wn * 256 + wm * 128 + m * 16 + rg + r] = vs[r];
    }
  }
  __syncthreads();

  // writer: even wn quarters emit their 128-block's (max, sum) per row
  if ((l & 15) == 0 && (wn & 1) == 0) {
    #pragma unroll
    for (int m = 0; m < 8; ++m)
      #pragma unroll
      for (int r = 0; r < 4; ++r) {
        int rr = wm * 128 + m * 16 + rg + r;
        float M = fmaxf(redmax[wn * 256 + rr], redmax[(wn + 1) * 256 + rr]);
        float L = redsum[wn * 256 + rr] + redsum[(wn + 1) * 256 + rr];
        Pstat[(crow0 + rr) * 64 + jb * 2 + (wn >> 1)] = make_float2(M, L);
      }
  }
}

// ==== gemm_pp: r17-proven ping-pong engine (__syncthreads, 32 KB LDS) ====
// MODE 3 only: split-K PV, DETERMINISTIC per-segment strip stores.
template <int MODE>
__global__ __launch_bounds__(256)
void gemm_pp(const f16* __restrict__ A, const f16* __restrict__ B,
             void* __restrict__ C, float2* __restrict__ Pstat, int q0, int q1, int SPLIT)
{
  __shared__ __align__(16) f16 As0[128 * 32];
  __shared__ __align__(16) f16 As1[128 * 32];
  __shared__ __align__(16) f16 Bs0[128 * 32];
  __shared__ __align__(16) f16 Bs1[128 * 32];

  const int tid = threadIdx.x;
  const int w = tid >> 6;
  const int l = tid & 63;
  const int wm = w >> 1, wn = w & 1;
  const int bid = xcd_swz();
  const int R = q1 - q0;

  int nk = 0, nb3 = 0, sseg3 = 0;
  const f16* Abase = nullptr;
  const f16* Bbase = nullptr;
  size_t crow0 = 0, ccol0 = 0;
  const int LDA = 2 * q1;
  const int LDBROW = 32;               // B row stride (panel-major vt)
  const size_t BADV = 32768;           // B per-K-step advance

  {
    int nqt = R >> 7;
    int per_b = nqt * 8 * SPLIT;
    int b = bid / per_b;
    int rem = bid % per_b;
    int qb = rem / (8 * SPLIT);
    int r2 = rem % (8 * SPLIT);
    nb3 = r2 / SPLIT;
    sseg3 = r2 % SPLIT;
    int nkt = (q0 >> 7) + qb + 1;      // total k-tiles for this q-block
    int len = (nkt + SPLIT - 1) / SPLIT;
    int t0 = sseg3 * len;
    int t1 = (t0 + len < nkt) ? t0 + len : nkt;
    if (t0 >= t1) return;              // unreachable for our chunk configs
    int k0s = t0 * 4;                  // starting K-step (32-wide)
    nk = (t1 - t0) * 4;                // even
    Abase = A + (size_t)(b * R + qb * 128) * 2 * q1 + (size_t)k0s * 32;   // P in-place
    Bbase = B + (size_t)b * 8388608 + (size_t)nb3 * 128 * 32 + (size_t)k0s * 32768;
    crow0 = (size_t)(b * R + qb * 128);
    ccol0 = (size_t)nb3 * 128;
  }

  f32x4 zero = {0.f, 0.f, 0.f, 0.f};
  f32x4 acc[4][4];
  #pragma unroll
  for (int m = 0; m < 4; ++m)
    #pragma unroll
    for (int n = 0; n < 4; ++n) acc[m][n] = zero;

  const int srow = l >> 2;
  const int skoff = (l & 3) * 8;
  const int lr = l & 15;
  const int kg = (l >> 4) * 8;
  const int rb0 = w * 16, rb1 = 64 + w * 16;

  const f16* gA0 = Abase + (size_t)(rb0 + srow) * LDA + skoff;
  const f16* gA1 = Abase + (size_t)(rb1 + srow) * LDA + skoff;
  const f16* gB0 = Bbase + (size_t)(rb0 + srow) * LDBROW + skoff;
  const f16* gB1 = Bbase + (size_t)(rb1 + srow) * LDBROW + skoff;

  const f16x8* rA0 = (const f16x8*)&As0[(wm * 64 + lr) * 32 + kg];
  const f16x8* rA1 = (const f16x8*)&As1[(wm * 64 + lr) * 32 + kg];
  const f16x8* rB0 = (const f16x8*)&Bs0[(wn * 64 + lr) * 32 + kg];
  const f16x8* rB1 = (const f16x8*)&Bs1[(wn * 64 + lr) * 32 + kg];

#define STAGE0() do { \
    gload_lds16(gA0, &As0[rb0 * 32]); gload_lds16(gA1, &As0[rb1 * 32]); \
    gload_lds16(gB0, &Bs0[rb0 * 32]); gload_lds16(gB1, &Bs0[rb1 * 32]); } while (0)
#define STAGE1() do { \
    gload_lds16(gA0, &As1[rb0 * 32]); gload_lds16(gA1, &As1[rb1 * 32]); \
    gload_lds16(gB0, &Bs1[rb0 * 32]); gload_lds16(gB1, &Bs1[rb1 * 32]); } while (0)
#define ADV() do { gA0 += 32; gA1 += 32; gB0 += BADV; gB1 += BADV; } while (0)
#define COMPUTE(rA, rB) do { \
    f16x8 av[4], bv[4]; \
    _Pragma("unroll") for (int m = 0; m < 4; ++m) av[m] = (rA)[m * 64]; \
    _Pragma("unroll") for (int n = 0; n < 4; ++n) bv[n] = (rB)[n * 64]; \
    _Pragma("unroll") for (int m = 0; m < 4; ++m) \
      _Pragma("unroll") for (int n = 0; n < 4; ++n) \
        acc[m][n] = __builtin_amdgcn_mfma_f32_16x16x32_f16(av[m], bv[n], acc[m][n], 0, 0, 0); \
  } while (0)

  STAGE0(); ADV();
  __syncthreads();
  for (int it = 0; it + 2 <= nk; it += 2) {
    STAGE1(); ADV();
    COMPUTE(rA0, rB0);
    __syncthreads();
    if (it + 2 < nk) { STAGE0(); }
    ADV();
    COMPUTE(rA1, rB1);
    __syncthreads();
  }
#undef STAGE0
#undef STAGE1
#undef ADV
#undef COMPUTE

  const int rg = (l >> 4) * 4;  // C/D: col = lane&15, row = (lane>>4)*4 + reg
  #pragma unroll
  for (int m = 0; m < 4; ++m) {
    #pragma unroll
    for (int n = 0; n < 4; ++n) {
      f32x4 v = acc[m][n];
      size_t coll = ccol0 + wn * 64 + n * 16 + lr;
      #pragma unroll
      for (int r = 0; r < 4; ++r) {
        size_t roww = crow0 + wm * 64 + m * 16 + rg + r;
        // strip sseg3: f32 offset q1/2 + 1024*sseg3 within the same S row
        ((float*)C)[roww * q1 + (q1 >> 1) + 1024 * sseg3 + coll] = v[r];
      }
    }
  }
  (void)Pstat;
}

extern "C" void kernel_launch(void* const* d_in, const int* in_sizes, int n_in,
                              void* d_out, int out_size, void* d_ws, size_t ws_size,
                              hipStream_t stream) {
  (void)in_sizes; (void)n_in;
  const float* x      = (const float*)d_in[0];
  const float* w_attn = (const float*)d_in[1];
  const float* b_attn = (const float*)d_in[2];
  const float* w_proj = (const float*)d_in[3];
  const float* b_proj = (const float*)d_in[4];
  float* out = (float*)d_out;

  const size_t WS_NEED = 268173312ull;  // 255.75 MiB
  if (ws_size < WS_NEED) {
    fprintf(stderr, "kernel_launch: ws_size=%zu < needed %zu -- skipping launches\n",
            ws_size, WS_NEED);
    hipMemsetAsync(d_out, 0, (size_t)out_size * 4, stream);
    return;
  }

  char* p = (char*)d_ws;
  f16* wA_h = (f16*)p; p += (size_t)3072 * 1024 * 2;        //   6.3 MB
  f16* wP_h = (f16*)p; p += (size_t)1024 * 1024 * 2;        //   2.1 MB
  f16* qkv  = (f16*)p; p += (size_t)16384 * 3072 * 2;       // 100.7 MB ([q|k|v] planes)
  f16* vt   = (f16*)p; p += (size_t)2 * 1024 * 8192 * 2;    //  33.6 MB (panel-major)
  f16* xo   = (f16*)p; p += (size_t)16384 * 1024 * 2;       //  33.6 MB (x_h, then o_h)
  float* S  = (float*)p; p += (size_t)2 * 3328 * 3328 * 4;  //  88.6 MB (scores; P + strips)
  float2* Pstat = (float2*)p; p += (size_t)2 * 3328 * 64 * 8; // 3.4 MB (row,block partials)
  // total 268,173,312 bytes

  k_cast<<<16384, 256, 0, stream>>>(x, xo, 4194304);
  k_cast<<<3072, 256, 0, stream>>>(w_attn, wA_h, 786432);
  k_cast<<<1024, 256, 0, stream>>>(w_proj, wP_h, 262144);
  hipLaunchKernelGGL(HIP_KERNEL_NAME(gemm_256<1>), dim3(768), dim3(512), 0, stream,
                     xo, wA_h, (void*)qkv, b_attn);
  k_rope<<<4096, 256, 0, stream>>>(qkv);
  k_transpose<<<4096, 256, 0, stream>>>(qkv, vt);

  // 4 variable chunks; S-GEMM (dense q/k planes, NT S-stores); PV split-K strips.
  const int Q0[4] = {0, 3328, 5376, 6912};
  const int Q1[4] = {3328, 5376, 6912, 8192};
  const int SP[4] = {1, 2, 3, 3};
  for (int c = 0; c < 4; ++c) {
    int q0 = Q0[c], q1 = Q1[c], R = q1 - q0;
    int nqt8 = R >> 8, ncb8 = q1 >> 8;   // 256-tiles
    int nqt = R >> 7;                    // 128-tiles (PV)
    gemm_s256<<<dim3(2 * nqt8 * ncb8), dim3(512), 0, stream>>>(qkv, S, Pstat, q0, q1);
    k_softmax_c<<<R / 2, 256, 0, stream>>>(S, Pstat, q0, q1);
    hipLaunchKernelGGL(HIP_KERNEL_NAME(gemm_pp<3>), dim3(2 * nqt * 8 * SP[c]), dim3(256), 0, stream,
                       (const f16*)S, vt, (void*)S, (float2*)nullptr, q0, q1, SP[c]);
    k_o_cast<<<2 * R, 256, 0, stream>>>(S, xo, q0, q1, SP[c]);
  }
  hipLaunchKernelGGL(HIP_KERNEL_NAME(gemm_256<4>), dim3(256), dim3(512), 0, stream,
                     xo, wP_h, (void*)out, b_proj);
}

// Round 30
// 901.979 us; speedup vs baseline: 1.0605x; 1.0605x over previous
//
#include <hip/hip_runtime.h>
#include <hip/hip_fp16.h>
#include <cstdio>

typedef _Float16 f16;
typedef _Float16 f16x8 __attribute__((ext_vector_type(8)));
typedef _Float16 f16x4 __attribute__((ext_vector_type(4)));
typedef float f32x4 __attribute__((ext_vector_type(4)));

#define DI __device__ __forceinline__

DI void gload_lds16(const void* g, void* l) {
  __builtin_amdgcn_global_load_lds(
      (const __attribute__((address_space(1))) void*)g,
      (__attribute__((address_space(3))) void*)l, 16, 0, 0);
}

// XCD-aware block swizzle (bijective when gridDim.x % 8 == 0) [T1]
DI int xcd_swz() {
  int nwg = gridDim.x, bid = blockIdx.x;
  if ((nwg & 7) == 0) bid = (bid & 7) * (nwg >> 3) + (bid >> 3);
  return bid;
}

// q/k/v plane offsets within the packed qkv region (f16 elements)
#define QK_PLANE 16777216   // 16384*1024

// ---------------- cast f32 -> f16, 4 elems/thread ----------------
__global__ void k_cast(const float* __restrict__ in, f16* __restrict__ out, int n4) {
  int i = blockIdx.x * blockDim.x + threadIdx.x;
  if (i >= n4) return;
  float4 v = ((const float4*)in)[i];
  f16x4 o;
  o[0] = (f16)v.x; o[1] = (f16)v.y; o[2] = (f16)v.z; o[3] = (f16)v.w;
  ((f16x4*)out)[i] = o;
}

// ---- O32 strips (in S upper halves) summed in FIXED order -> xo f16 rows --------
__global__ void k_o_cast(const float* __restrict__ S, f16* __restrict__ xo,
                         int q0, int q1, int SPLIT) {
  int R = q1 - q0;
  int i = blockIdx.x * blockDim.x + threadIdx.x;   // 2R * 256 threads
  int grow = i >> 8;
  int c4 = (i & 255) * 4;
  const float* strip = S + (size_t)grow * q1 + (q1 >> 1);
  float4 v = *(const float4*)(strip + c4);
  if (SPLIT > 1) {
    float4 v1 = *(const float4*)(strip + 1024 + c4);
    v.x += v1.x; v.y += v1.y; v.z += v1.z; v.w += v1.w;
  }
  if (SPLIT > 2) {
    float4 v2 = *(const float4*)(strip + 2048 + c4);
    v.x += v2.x; v.y += v2.y; v.z += v2.z; v.w += v2.w;
  }
  int b = (grow >= R) ? 1 : 0;
  int qloc = grow - b * R;
  f16x4 o;
  o[0] = (f16)v.x; o[1] = (f16)v.y; o[2] = (f16)v.z; o[3] = (f16)v.w;
  *(f16x4*)(xo + (size_t)(b * 8192 + q0 + qloc) * 1024 + c4) = o;
}

// ---------------- RoPE in-place on separate q/k planes (stride 1024) -------------
__global__ void k_rope(f16* __restrict__ qkv) {
  int gid = blockIdx.x * blockDim.x + threadIdx.x;  // 16384 * 64
  int tt = gid >> 6, j0 = (gid & 63) * 8;
  int t = tt & 8191;
  f16* rowq = qkv + (size_t)tt * 1024;
  f16* rowk = qkv + QK_PLANE + (size_t)tt * 1024;
  f16x8 qa = *(f16x8*)(rowq + j0), qb = *(f16x8*)(rowq + 512 + j0);
  f16x8 ka = *(f16x8*)(rowk + j0), kb = *(f16x8*)(rowk + 512 + j0);
  #pragma unroll
  for (int u = 0; u < 8; ++u) {
    int j = j0 + u;
    float invf = powf(10000.0f, -(float)j * (1.0f / 512.0f));
    float s, c;
    sincosf((float)t * invf, &s, &c);
    float q0v = (float)qa[u], q1v = (float)qb[u];
    qa[u] = (f16)(q0v * c - q1v * s); qb[u] = (f16)(q1v * c + q0v * s);
    float k0v = (float)ka[u], k1v = (float)kb[u];
    ka[u] = (f16)(k0v * c - k1v * s); kb[u] = (f16)(k1v * c + k0v * s);
  }
  *(f16x8*)(rowq + j0) = qa; *(f16x8*)(rowq + 512 + j0) = qb;
  *(f16x8*)(rowk + j0) = ka; *(f16x8*)(rowk + 512 + j0) = kb;
}

// ---------------- V transpose: v plane -> vt PANEL-MAJOR [t/32][d][32] ----------
__global__ __launch_bounds__(256) void k_transpose(const f16* __restrict__ qkv, f16* __restrict__ vt) {
  __shared__ f16 tile[64][72];
  int bid = blockIdx.x;            // 2 * 128 * 16
  int b = bid >> 11;
  int rem = bid & 2047;
  int tb = (rem >> 4) * 64;        // token base
  int db = (rem & 15) * 64;        // d base
  int tid = threadIdx.x;
  int r = tid >> 2, c0 = (tid & 3) * 16;
  const f16* src = qkv + (size_t)2 * QK_PLANE + (size_t)(b * 8192 + tb + r) * 1024 + db + c0;
  #pragma unroll
  for (int ii = 0; ii < 16; ++ii) tile[r][c0 + ii] = src[ii];
  __syncthreads();
  int p = (tb + c0) >> 5;
  int t5 = (tb + c0) & 31;
  f16* dst = vt + (size_t)b * 8388608 + (size_t)p * 32768 + (size_t)(db + r) * 32 + t5;
  #pragma unroll
  for (int ii = 0; ii < 16; ++ii) dst[ii] = tile[c0 + ii][r];
}

// -------- chunk softmax: pass1 from Pstat partials; pass2 in-place S->P ----------
__global__ __launch_bounds__(256)
void k_softmax_c(float* __restrict__ S, const float2* __restrict__ Pstat, int q0, int q1) {
  int R = q1 - q0;
  int row = blockIdx.x * 4 + (threadIdx.x >> 6);  // 0..2R-1
  int lane = threadIdx.x & 63;
  int b = (row >= R) ? 1 : 0;
  int qloc = row - b * R;
  int qg = q0 + qloc;
  float* Srow = S + (size_t)row * q1;
  int nvalid = qg + 1;
  int djb = qg >> 7;                // last valid 128-col block for this row

  float2 st = make_float2(-INFINITY, 0.f);
  if (lane <= djb) st = Pstat[(size_t)row * 64 + lane];
  float m = st.x;
  #pragma unroll
  for (int msk = 32; msk >= 1; msk >>= 1) m = fmaxf(m, __shfl_xor(m, msk));
  float contrib = (lane <= djb) ? st.y * __expf(st.x - m) : 0.f;
  #pragma unroll
  for (int msk = 32; msk >= 1; msk >>= 1) contrib += __shfl_xor(contrib, msk);
  float ssum = contrib;

  float rinv = 0.03125f / ssum;  // 1024^-0.5 applied post-softmax (reference quirk)
  int klim = (qg | 127) + 1;     // zero-fill to PV's k-tile boundary
  f16* Prow = (f16*)Srow;
  for (int kk = lane * 4; kk < klim; kk += 256) {
    float4 v = *(const float4*)(Srow + kk);
    asm volatile("" ::: "memory");  // keep f32 load before aliasing f16 store
    f16x4 o;
    o[0] = (f16)((kk     < nvalid) ? __expf(v.x - m) * rinv : 0.f);
    o[1] = (f16)((kk + 1 < nvalid) ? __expf(v.y - m) * rinv : 0.f);
    o[2] = (f16)((kk + 2 < nvalid) ? __expf(v.z - m) * rinv : 0.f);
    o[3] = (f16)((kk + 3 < nvalid) ? __expf(v.w - m) * rinv : 0.f);
    *(f16x4*)(Prow + kk) = o;
  }
}

// ==== gemm_256: 256x256 tile, 8 waves, BK=32, ring-4, counted vmcnt [T3/T4] + T2 ====
// MODE 1: qkv proj -> separate q/k/v planes (bn>>2 selects plane), fp16
// MODE 4: out = o @ w_proj^T + b -> fp32
template <int MODE>
__global__ __launch_bounds__(512)
void gemm_256(const f16* __restrict__ A, const f16* __restrict__ B,
              void* __restrict__ C, const float* __restrict__ bias)
{
  __shared__ __align__(16) f16 As[4][8192];
  __shared__ __align__(16) f16 Bs[4][8192];

  const int tid = threadIdx.x;
  const int w = tid >> 6;
  const int l = tid & 63;
  const int wm = w >> 2;
  const int wn = w & 3;
  const int bid = xcd_swz();

  int bm, bn;
  if constexpr (MODE == 1) {
    int grp = bid >> 3, off = bid & 7;
    bm = (grp / 6) * 4 + (off >> 1);
    bn = (grp % 6) * 2 + (off & 1);
  } else {
    bm = bid >> 2; bn = bid & 3;
  }
  const int nk = 32;
  const f16* Abase = A + (size_t)bm * 256 * 1024;
  const f16* Bbase = B + (size_t)bn * 256 * 1024;

  f32x4 acc[8][4];
  #pragma unroll
  for (int m = 0; m < 8; ++m)
    #pragma unroll
    for (int n = 0; n < 4; ++n) { acc[m][n][0]=0.f; acc[m][n][1]=0.f; acc[m][n][2]=0.f; acc[m][n][3]=0.f; }

  const int srow = tid >> 2;
  const int swz = ((tid & 3) ^ ((tid >> 3) & 3)) * 8;   // T2 writer-side
  const f16* gA0 = Abase + (size_t)srow * 1024 + swz;
  const f16* gA1 = gA0 + (size_t)128 * 1024;
  const f16* gB0 = Bbase + (size_t)srow * 1024 + swz;
  const f16* gB1 = gB0 + (size_t)128 * 1024;
  const int ldst = tid * 8;

  const int pch = (l >> 4) ^ (((l & 15) >> 1) & 3);     // T2 reader-side
  const int aoffb = (wm * 128 + (l & 15)) * 32 + pch * 8;
  const int boffb = (wn * 64 + (l & 15)) * 32 + pch * 8;

#define STAGE(slot, t) do { \
    const size_t _o = (size_t)(t) * 32; \
    f16* _as = As[slot]; f16* _bs = Bs[slot]; \
    gload_lds16(gA0 + _o, _as + ldst); \
    gload_lds16(gA1 + _o, _as + 4096 + ldst); \
    gload_lds16(gB0 + _o, _bs + ldst); \
    gload_lds16(gB1 + _o, _bs + 4096 + ldst); } while (0)
#define COMPUTE(slot) do { \
    const f16* pa = As[slot] + aoffb; \
    const f16* pb = Bs[slot] + boffb; \
    f16x8 av[8], bv[4]; \
    _Pragma("unroll") for (int m = 0; m < 8; ++m) av[m] = *(const f16x8*)(pa + m * 512); \
    _Pragma("unroll") for (int n = 0; n < 4; ++n) bv[n] = *(const f16x8*)(pb + n * 512); \
    _Pragma("unroll") for (int m = 0; m < 8; ++m) \
      _Pragma("unroll") for (int n = 0; n < 4; ++n) \
        acc[m][n] = __builtin_amdgcn_mfma_f32_16x16x32_f16(av[m], bv[n], acc[m][n], 0, 0, 0); \
  } while (0)

  STAGE(0, 0); STAGE(1, 1);
  for (int i = 0; i < nk; ++i) {
    int ts = (i + 2 < nk) ? i + 2 : nk - 1;
    STAGE((i + 2) & 3, ts);
    asm volatile("s_waitcnt vmcnt(8)" ::: "memory");
    __builtin_amdgcn_s_barrier();
    COMPUTE(i & 3);
  }
#undef STAGE
#undef COMPUTE

  const int rg = (l >> 4) * 4;
  #pragma unroll
  for (int m = 0; m < 8; ++m) {
    #pragma unroll
    for (int n = 0; n < 4; ++n) {
      f32x4 v = acc[m][n];
      size_t colg = (size_t)bn * 256 + wn * 64 + n * 16 + (l & 15);
      #pragma unroll
      for (int r = 0; r < 4; ++r) {
        size_t roww = (size_t)bm * 256 + wm * 128 + m * 16 + rg + r;
        if constexpr (MODE == 1) {
          // route to q/k/v plane: bn in [0,12), each 256-col tile within one plane
          f16* dst = (f16*)C + (size_t)(bn >> 2) * QK_PLANE;
          size_t col = colg & 1023;
          dst[roww * 1024 + col] = (f16)(v[r] + bias[colg]);
        } else {
          ((float*)C)[roww * 1024 + colg] = v[r] + bias[colg];
        }
      }
    }
  }
}

// ==== gemm_s256: S-GEMM, 256x256 tile, 8 waves, 2-PHASE syncthreads ping-pong ====
// A = q plane (stride 1024), B = k plane (stride 1024): 3x denser page footprint
// than the old interleaved-qkv stride-3072 reads. S-write m{r{n}} (contiguous).
__global__ __launch_bounds__(512)
void gemm_s256(const f16* __restrict__ A, float* __restrict__ S,
               float2* __restrict__ Pstat, int q0, int q1)
{
  __shared__ __align__(16) f16 As0[8192];   // 256x32 f16 = 16 KB
  __shared__ __align__(16) f16 As1[8192];
  __shared__ __align__(16) f16 Bs0[8192];
  __shared__ __align__(16) f16 Bs1[8192];   // total 64 KB -> 2 blocks/CU

  const int tid = threadIdx.x;
  const int w = tid >> 6;
  const int l = tid & 63;
  const int wm = w >> 2;
  const int wn = w & 3;
  const int bid = xcd_swz();
  const int R = q1 - q0;
  const int nqt = R >> 8, ncb = q1 >> 8;

  int b = bid / (nqt * ncb);
  int rem = bid % (nqt * ncb);
  int qb = rem / ncb, jb = rem % ncb;
  const int jdiag = (q0 >> 8) + qb;
  if (jb > jdiag) return;             // fully-masked (block-uniform, pre-barrier)

  const f16* Abase = A + (size_t)(b * 8192 + q0 + qb * 256) * 1024;              // q rows
  const f16* Bbase = A + QK_PLANE + (size_t)(b * 8192 + jb * 256) * 1024;        // k rows
  const size_t crow0 = (size_t)(b * R + qb * 256);
  const int nk = 32;

  f32x4 acc[8][4];
  #pragma unroll
  for (int m = 0; m < 8; ++m)
    #pragma unroll
    for (int n = 0; n < 4; ++n) { acc[m][n][0]=0.f; acc[m][n][1]=0.f; acc[m][n][2]=0.f; acc[m][n][3]=0.f; }

  const int srow = tid >> 2;
  const int swz = ((tid & 3) ^ ((tid >> 3) & 3)) * 8;   // T2 writer-side
  const f16* gA0 = Abase + (size_t)srow * 1024 + swz;
  const f16* gA1 = gA0 + (size_t)128 * 1024;
  const f16* gB0 = Bbase + (size_t)srow * 1024 + swz;
  const f16* gB1 = gB0 + (size_t)128 * 1024;
  const int ldst = tid * 8;

  const int pch = (l >> 4) ^ (((l & 15) >> 1) & 3);     // T2 reader-side
  const int aoffb = (wm * 128 + (l & 15)) * 32 + pch * 8;
  const int boffb = (wn * 64 + (l & 15)) * 32 + pch * 8;

#define STAGE0() do { \
    gload_lds16(gA0, As0 + ldst); gload_lds16(gA1, As0 + 4096 + ldst); \
    gload_lds16(gB0, Bs0 + ldst); gload_lds16(gB1, Bs0 + 4096 + ldst); } while (0)
#define STAGE1() do { \
    gload_lds16(gA0, As1 + ldst); gload_lds16(gA1, As1 + 4096 + ldst); \
    gload_lds16(gB0, Bs1 + ldst); gload_lds16(gB1, Bs1 + 4096 + ldst); } while (0)
#define ADV() do { gA0 += 32; gA1 += 32; gB0 += 32; gB1 += 32; } while (0)
#define COMPUTE(as_, bs_) do { \
    const f16* pa = (as_) + aoffb; \
    const f16* pb = (bs_) + boffb; \
    f16x8 av[8], bv[4]; \
    _Pragma("unroll") for (int m = 0; m < 8; ++m) av[m] = *(const f16x8*)(pa + m * 512); \
    _Pragma("unroll") for (int n = 0; n < 4; ++n) bv[n] = *(const f16x8*)(pb + n * 512); \
    _Pragma("unroll") for (int m = 0; m < 8; ++m) \
      _Pragma("unroll") for (int n = 0; n < 4; ++n) \
        acc[m][n] = __builtin_amdgcn_mfma_f32_16x16x32_f16(av[m], bv[n], acc[m][n], 0, 0, 0); \
  } while (0)

  STAGE0(); ADV();
  __syncthreads();
  for (int it = 0; it + 2 <= nk; it += 2) {
    STAGE1(); ADV();
    COMPUTE(As0, Bs0);
    __syncthreads();
    if (it + 2 < nk) { STAGE0(); }
    ADV();
    COMPUTE(As1, Bs1);
    __syncthreads();
  }
#undef STAGE0
#undef STAGE1
#undef ADV
#undef COMPUTE

  const int rg = (l >> 4) * 4;  // C/D: col = lane&15, row = (lane>>4)*4 + reg
  // ---- S write: n-innermost (contiguous 256B run per 16-lane group) ----
  #pragma unroll
  for (int m = 0; m < 8; ++m) {
    #pragma unroll
    for (int r = 0; r < 4; ++r) {
      size_t roww = crow0 + wm * 128 + m * 16 + rg + r;
      float* sp = S + roww * q1 + (size_t)jb * 256 + wn * 64 + (l & 15);
      #pragma unroll
      for (int n = 0; n < 4; ++n)
        sp[n * 16] = acc[m][n][r];
    }
  }

  // ---- Pstat partials: reuse dead LDS (As0 = max, Bs0 = sums), fixed order ----
  __syncthreads();                       // all waves past last LDS tile reads
  float* redmax = (float*)As0;           // [4][256] f32 (wn-indexed)
  float* redsum = (float*)Bs0;           // [4][256] f32
  const bool diag = (jb == jdiag);
  const int cbase = jb * 256 + wn * 64 + (l & 15);
  const int rbase = q0 + qb * 256 + wm * 128;

  // pass 1: per-row masked max over this lane's 4 cols, shfl over 16-lane col group
  #pragma unroll
  for (int m = 0; m < 8; ++m) {
    float vm[4];
    #pragma unroll
    for (int r = 0; r < 4; ++r) {
      int row_g = rbase + m * 16 + rg + r;
      float best = -INFINITY;
      #pragma unroll
      for (int n = 0; n < 4; ++n) {
        bool valid = !diag || (cbase + n * 16 <= row_g);
        if (valid) best = fmaxf(best, acc[m][n][r]);
      }
      vm[r] = best;
    }
    #pragma unroll
    for (int r = 0; r < 4; ++r)
      #pragma unroll
      for (int msk = 1; msk <= 8; msk <<= 1)
        vm[r] = fmaxf(vm[r], __shfl_xor(vm[r], msk));
    if ((l & 15) == 0) {
      #pragma unroll
      for (int r = 0; r < 4; ++r)
        redmax[wn * 256 + wm * 128 + m * 16 + rg + r] = vm[r];
    }
  }
  __syncthreads();

  // pass 2: sumexp with the 128-block max (pair of wn quarters), shfl, store
  #pragma unroll
  for (int m = 0; m < 8; ++m) {
    float vs[4];
    #pragma unroll
    for (int r = 0; r < 4; ++r) {
      int rr = wm * 128 + m * 16 + rg + r;
      float Mv = fmaxf(redmax[(wn & ~1) * 256 + rr], redmax[(wn | 1) * 256 + rr]);
      int row_g = rbase + m * 16 + rg + r;
      float s = 0.f;
      #pragma unroll
      for (int n = 0; n < 4; ++n) {
        bool valid = !diag || (cbase + n * 16 <= row_g);
        if (valid) s += __expf(acc[m][n][r] - Mv);
      }
      vs[r] = s;
    }
    #pragma unroll
    for (int r = 0; r < 4; ++r)
      #pragma unroll
      for (int msk = 1; msk <= 8; msk <<= 1)
        vs[r] += __shfl_xor(vs[r], msk);
    if ((l & 15) == 0) {
      #pragma unroll
      for (int r = 0; r < 4; ++r)
        redsum[wn * 256 + wm * 128 + m * 16 + rg + r] = vs[r];
    }
  }
  __syncthreads();

  // writer: even wn quarters emit their 128-block's (max, sum) per row
  if ((l & 15) == 0 && (wn & 1) == 0) {
    #pragma unroll
    for (int m = 0; m < 8; ++m)
      #pragma unroll
      for (int r = 0; r < 4; ++r) {
        int rr = wm * 128 + m * 16 + rg + r;
        float M = fmaxf(redmax[wn * 256 + rr], redmax[(wn + 1) * 256 + rr]);
        float L = redsum[wn * 256 + rr] + redsum[(wn + 1) * 256 + rr];
        Pstat[(crow0 + rr) * 64 + jb * 2 + (wn >> 1)] = make_float2(M, L);
      }
  }
}

// ==== gemm_pp: r17-proven ping-pong engine (__syncthreads, 32 KB LDS) ====
// MODE 3 only: split-K PV, DETERMINISTIC per-segment strip stores.
template <int MODE>
__global__ __launch_bounds__(256)
void gemm_pp(const f16* __restrict__ A, const f16* __restrict__ B,
             void* __restrict__ C, float2* __restrict__ Pstat, int q0, int q1, int SPLIT)
{
  __shared__ __align__(16) f16 As0[128 * 32];
  __shared__ __align__(16) f16 As1[128 * 32];
  __shared__ __align__(16) f16 Bs0[128 * 32];
  __shared__ __align__(16) f16 Bs1[128 * 32];

  const int tid = threadIdx.x;
  const int w = tid >> 6;
  const int l = tid & 63;
  const int wm = w >> 1, wn = w & 1;
  const int bid = xcd_swz();
  const int R = q1 - q0;

  int nk = 0, nb3 = 0, sseg3 = 0;
  const f16* Abase = nullptr;
  const f16* Bbase = nullptr;
  size_t crow0 = 0, ccol0 = 0;
  const int LDA = 2 * q1;
  const int LDBROW = 32;               // B row stride (panel-major vt)
  const size_t BADV = 32768;           // B per-K-step advance

  {
    int nqt = R >> 7;
    int per_b = nqt * 8 * SPLIT;
    int b = bid / per_b;
    int rem = bid % per_b;
    int qb = rem / (8 * SPLIT);
    int r2 = rem % (8 * SPLIT);
    nb3 = r2 / SPLIT;
    sseg3 = r2 % SPLIT;
    int nkt = (q0 >> 7) + qb + 1;      // total k-tiles for this q-block
    int len = (nkt + SPLIT - 1) / SPLIT;
    int t0 = sseg3 * len;
    int t1 = (t0 + len < nkt) ? t0 + len : nkt;
    if (t0 >= t1) return;              // unreachable for our chunk configs
    int k0s = t0 * 4;                  // starting K-step (32-wide)
    nk = (t1 - t0) * 4;                // even
    Abase = A + (size_t)(b * R + qb * 128) * 2 * q1 + (size_t)k0s * 32;   // P in-place
    Bbase = B + (size_t)b * 8388608 + (size_t)nb3 * 128 * 32 + (size_t)k0s * 32768;
    crow0 = (size_t)(b * R + qb * 128);
    ccol0 = (size_t)nb3 * 128;
  }

  f32x4 zero = {0.f, 0.f, 0.f, 0.f};
  f32x4 acc[4][4];
  #pragma unroll
  for (int m = 0; m < 4; ++m)
    #pragma unroll
    for (int n = 0; n < 4; ++n) acc[m][n] = zero;

  const int srow = l >> 2;
  const int skoff = (l & 3) * 8;
  const int lr = l & 15;
  const int kg = (l >> 4) * 8;
  const int rb0 = w * 16, rb1 = 64 + w * 16;

  const f16* gA0 = Abase + (size_t)(rb0 + srow) * LDA + skoff;
  const f16* gA1 = Abase + (size_t)(rb1 + srow) * LDA + skoff;
  const f16* gB0 = Bbase + (size_t)(rb0 + srow) * LDBROW + skoff;
  const f16* gB1 = Bbase + (size_t)(rb1 + srow) * LDBROW + skoff;

  const f16x8* rA0 = (const f16x8*)&As0[(wm * 64 + lr) * 32 + kg];
  const f16x8* rA1 = (const f16x8*)&As1[(wm * 64 + lr) * 32 + kg];
  const f16x8* rB0 = (const f16x8*)&Bs0[(wn * 64 + lr) * 32 + kg];
  const f16x8* rB1 = (const f16x8*)&Bs1[(wn * 64 + lr) * 32 + kg];

#define STAGE0() do { \
    gload_lds16(gA0, &As0[rb0 * 32]); gload_lds16(gA1, &As0[rb1 * 32]); \
    gload_lds16(gB0, &Bs0[rb0 * 32]); gload_lds16(gB1, &Bs0[rb1 * 32]); } while (0)
#define STAGE1() do { \
    gload_lds16(gA0, &As1[rb0 * 32]); gload_lds16(gA1, &As1[rb1 * 32]); \
    gload_lds16(gB0, &Bs1[rb0 * 32]); gload_lds16(gB1, &Bs1[rb1 * 32]); } while (0)
#define ADV() do { gA0 += 32; gA1 += 32; gB0 += BADV; gB1 += BADV; } while (0)
#define COMPUTE(rA, rB) do { \
    f16x8 av[4], bv[4]; \
    _Pragma("unroll") for (int m = 0; m < 4; ++m) av[m] = (rA)[m * 64]; \
    _Pragma("unroll") for (int n = 0; n < 4; ++n) bv[n] = (rB)[n * 64]; \
    _Pragma("unroll") for (int m = 0; m < 4; ++m) \
      _Pragma("unroll") for (int n = 0; n < 4; ++n) \
        acc[m][n] = __builtin_amdgcn_mfma_f32_16x16x32_f16(av[m], bv[n], acc[m][n], 0, 0, 0); \
  } while (0)

  STAGE0(); ADV();
  __syncthreads();
  for (int it = 0; it + 2 <= nk; it += 2) {
    STAGE1(); ADV();
    COMPUTE(rA0, rB0);
    __syncthreads();
    if (it + 2 < nk) { STAGE0(); }
    ADV();
    COMPUTE(rA1, rB1);
    __syncthreads();
  }
#undef STAGE0
#undef STAGE1
#undef ADV
#undef COMPUTE

  const int rg = (l >> 4) * 4;  // C/D: col = lane&15, row = (lane>>4)*4 + reg
  #pragma unroll
  for (int m = 0; m < 4; ++m) {
    #pragma unroll
    for (int n = 0; n < 4; ++n) {
      f32x4 v = acc[m][n];
      size_t coll = ccol0 + wn * 64 + n * 16 + lr;
      #pragma unroll
      for (int r = 0; r < 4; ++r) {
        size_t roww = crow0 + wm * 64 + m * 16 + rg + r;
        // strip sseg3: f32 offset q1/2 + 1024*sseg3 within the same S row
        ((float*)C)[roww * q1 + (q1 >> 1) + 1024 * sseg3 + coll] = v[r];
      }
    }
  }
  (void)Pstat;
}

extern "C" void kernel_launch(void* const* d_in, const int* in_sizes, int n_in,
                              void* d_out, int out_size, void* d_ws, size_t ws_size,
                              hipStream_t stream) {
  (void)in_sizes; (void)n_in;
  const float* x      = (const float*)d_in[0];
  const float* w_attn = (const float*)d_in[1];
  const float* b_attn = (const float*)d_in[2];
  const float* w_proj = (const float*)d_in[3];
  const float* b_proj = (const float*)d_in[4];
  float* out = (float*)d_out;

  const size_t WS_NEED = 268173312ull;  // 255.75 MiB
  if (ws_size < WS_NEED) {
    fprintf(stderr, "kernel_launch: ws_size=%zu < needed %zu -- skipping launches\n",
            ws_size, WS_NEED);
    hipMemsetAsync(d_out, 0, (size_t)out_size * 4, stream);
    return;
  }

  char* p = (char*)d_ws;
  f16* wA_h = (f16*)p; p += (size_t)3072 * 1024 * 2;        //   6.3 MB
  f16* wP_h = (f16*)p; p += (size_t)1024 * 1024 * 2;        //   2.1 MB
  f16* qkv  = (f16*)p; p += (size_t)16384 * 3072 * 2;       // 100.7 MB ([q|k|v] planes)
  f16* vt   = (f16*)p; p += (size_t)2 * 1024 * 8192 * 2;    //  33.6 MB (panel-major)
  f16* xo   = (f16*)p; p += (size_t)16384 * 1024 * 2;       //  33.6 MB (x_h, then o_h)
  float* S  = (float*)p; p += (size_t)2 * 3328 * 3328 * 4;  //  88.6 MB (scores; P + strips)
  float2* Pstat = (float2*)p; p += (size_t)2 * 3328 * 64 * 8; // 3.4 MB (row,block partials)
  // total 268,173,312 bytes

  k_cast<<<16384, 256, 0, stream>>>(x, xo, 4194304);
  k_cast<<<3072, 256, 0, stream>>>(w_attn, wA_h, 786432);
  k_cast<<<1024, 256, 0, stream>>>(w_proj, wP_h, 262144);
  hipLaunchKernelGGL(HIP_KERNEL_NAME(gemm_256<1>), dim3(768), dim3(512), 0, stream,
                     xo, wA_h, (void*)qkv, b_attn);
  k_rope<<<4096, 256, 0, stream>>>(qkv);
  k_transpose<<<4096, 256, 0, stream>>>(qkv, vt);

  // 4 variable chunks; S-GEMM on the 256^2 2-phase engine reading dense q/k planes;
  // PV split-K via per-segment strips (plain stores, fixed-order sum).
  const int Q0[4] = {0, 3328, 5376, 6912};
  const int Q1[4] = {3328, 5376, 6912, 8192};
  const int SP[4] = {1, 2, 3, 3};
  for (int c = 0; c < 4; ++c) {
    int q0 = Q0[c], q1 = Q1[c], R = q1 - q0;
    int nqt8 = R >> 8, ncb8 = q1 >> 8;   // 256-tiles
    int nqt = R >> 7;                    // 128-tiles (PV)
    gemm_s256<<<dim3(2 * nqt8 * ncb8), dim3(512), 0, stream>>>(qkv, S, Pstat, q0, q1);
    k_softmax_c<<<R / 2, 256, 0, stream>>>(S, Pstat, q0, q1);
    hipLaunchKernelGGL(HIP_KERNEL_NAME(gemm_pp<3>), dim3(2 * nqt * 8 * SP[c]), dim3(256), 0, stream,
                       (const f16*)S, vt, (void*)S, (float2*)nullptr, q0, q1, SP[c]);
    k_o_cast<<<2 * R, 256, 0, stream>>>(S, xo, q0, q1, SP[c]);
  }
  hipLaunchKernelGGL(HIP_KERNEL_NAME(gemm_256<4>), dim3(256), dim3(512), 0, stream,
                     xo, wP_h, (void*)out, b_proj);
}